// Round 1
// baseline (778.494 us; speedup 1.0000x reference)
//
#include <hip/hip_runtime.h>
#include <math.h>

#define LL 2048
#define FF 352
#define BATCH 8
#define TOPK 84
#define FPB 4                 // f-rows per score block
#define BPB (FF / FPB)        // 88 blocks per batch
#define NCAND (BPB * TOPK)    // 7392 candidates per batch

// ws float-index layout
#define OFF_A 0
#define OFF_B 16
#define OFF_C 32
#define OFF_D 48
#define OFF_Q 64                          // 48 floats
#define OFF_CS 256                        // 8*7392 floats (candidate scores)
#define OFF_CI (256 + BATCH * NCAND)      // 8*7392 ints  (candidate indices)

__global__ void k_zero(float* ws) {
    if (threadIdx.x < 64) ws[threadIdx.x] = 0.f;
}

// One block per (b,ch,f) row: row sum -> A, plus x[0]->B, x[1]->C, x[L-1]->D
__global__ __launch_bounds__(256) void k_rowsum(const float* __restrict__ x,
                                                float* __restrict__ ws) {
    int r = blockIdx.x;              // (b*2+ch)*352 + f
    int bc = r / FF;
    const float4* rp = (const float4*)(x + (size_t)r * LL);
    int tid = threadIdx.x;
    float4 v0 = rp[tid];
    float4 v1 = rp[tid + 256];
    float s = v0.x + v0.y + v0.z + v0.w + v1.x + v1.y + v1.z + v1.w;
    for (int off = 32; off; off >>= 1) s += __shfl_down(s, off);
    __shared__ float red[4];
    int lane = tid & 63, wid = tid >> 6;
    if (lane == 0) red[wid] = s;
    __syncthreads();
    if (tid == 0) {
        atomicAdd(&ws[OFF_A + bc], red[0] + red[1] + red[2] + red[3]);
        atomicAdd(&ws[OFF_B + bc], v0.x);
        atomicAdd(&ws[OFF_C + bc], v0.y);
    }
    if (tid == 255) atomicAdd(&ws[OFF_D + bc], v1.w);
}

// query[b][e], e = i*2+ch: closed form of the shifted means
__global__ void k_query(float* ws) {
    int tid = threadIdx.x;
    if (tid < 48) {
        int e = tid % 6, i = e >> 1, ch = e & 1;
        int bc = (tid / 6) * 2 + ch;
        float A = ws[OFF_A + bc], B = ws[OFF_B + bc];
        float C = ws[OFF_C + bc], D = ws[OFF_D + bc];
        float S = (i == 0) ? A : (i == 1 ? A - B + D : A - B - C + 2.f * D);
        ws[OFF_Q + tid] = S * (1.f / (float)(FF * LL));
    }
}

// Scores for 4 f-rows (8192 scores) in LDS + local top-84 via iterative max
__global__ __launch_bounds__(256) void k_scores(const float* __restrict__ x,
                                                float* __restrict__ ws,
                                                int* __restrict__ wsi) {
    __shared__ float rb0[LL], rb1[LL];
    __shared__ float sc[FPB * LL];
    __shared__ float redv[4];
    __shared__ int redp[4];
    int tid = threadIdx.x;
    int b = blockIdx.x / BPB, blk = blockIdx.x % BPB;
    int fb = blk * FPB;
    float q0 = ws[OFF_Q + b * 6 + 0], q1 = ws[OFF_Q + b * 6 + 1];
    float q2 = ws[OFF_Q + b * 6 + 2], q3 = ws[OFF_Q + b * 6 + 3];
    float q4 = ws[OFF_Q + b * 6 + 4], q5 = ws[OFF_Q + b * 6 + 5];

    for (int fr = 0; fr < FPB; ++fr) {
        int f = fb + fr;
        const float4* r0 = (const float4*)(x + ((size_t)(b * 2 + 0) * FF + f) * LL);
        const float4* r1 = (const float4*)(x + ((size_t)(b * 2 + 1) * FF + f) * LL);
        __syncthreads();
        ((float4*)rb0)[tid] = r0[tid];
        ((float4*)rb0)[tid + 256] = r0[tid + 256];
        ((float4*)rb1)[tid] = r1[tid];
        ((float4*)rb1)[tid + 256] = r1[tid + 256];
        __syncthreads();
        for (int k = 0; k < 8; ++k) {
            int l = tid + (k << 8);
            int l1 = l + 1 < LL ? l + 1 : LL - 1;
            int l2 = l + 2 < LL ? l + 2 : LL - 1;
            float s = q0 * rb0[l] + q1 * rb1[l];
            s += q2 * rb0[l1] + q3 * rb1[l1];
            s += q4 * rb0[l2] + q5 * rb1[l2];
            sc[fr * LL + l] = s;
        }
    }
    __syncthreads();

    int lane = tid & 63, wid = tid >> 6;
    int obase = (b * BPB + blk) * TOPK;
    for (int it = 0; it < TOPK; ++it) {
        float bv = -INFINITY;
        int bp = 1 << 30;
        for (int k = 0; k < 32; ++k) {
            int p = tid + (k << 8);
            float v = sc[p];
            if (v > bv || (v == bv && p < bp)) { bv = v; bp = p; }
        }
        for (int off = 32; off; off >>= 1) {
            float ov = __shfl_down(bv, off);
            int op = __shfl_down(bp, off);
            if (ov > bv || (ov == bv && op < bp)) { bv = ov; bp = op; }
        }
        if (lane == 0) { redv[wid] = bv; redp[wid] = bp; }
        __syncthreads();
        if (tid == 0) {
            for (int w2 = 1; w2 < 4; ++w2) {
                float ov = redv[w2]; int op = redp[w2];
                if (ov > bv || (ov == bv && op < bp)) { bv = ov; bp = op; }
            }
            ws[OFF_CS + obase + it] = bv;
            wsi[OFF_CI + obase + it] = fb * LL + bp;  // global n in batch
            sc[bp] = -INFINITY;
        }
        __syncthreads();
    }
}

// One block per batch: merge 7392 candidates -> top-84, softmax, gather, output
__global__ __launch_bounds__(256) void k_final(const float* __restrict__ x,
                                               const float* __restrict__ wv,
                                               const float* __restrict__ ws,
                                               const int* __restrict__ wsi,
                                               float* __restrict__ out) {
    __shared__ float cs[NCAND];
    __shared__ int ci[NCAND];
    __shared__ float selv[TOPK];
    __shared__ int seli[TOPK];
    __shared__ float redv[4];
    __shared__ int redp[4];
    __shared__ float redsum[4];
    __shared__ float acc[8];
    int tid = threadIdx.x;
    int b = blockIdx.x;
    for (int k = 0; k < 29; ++k) {
        int p = tid + (k << 8);
        if (p < NCAND) {
            cs[p] = ws[OFF_CS + b * NCAND + p];
            ci[p] = wsi[OFF_CI + b * NCAND + p];
        }
    }
    if (tid < 8) acc[tid] = 0.f;
    __syncthreads();

    int lane = tid & 63, wid = tid >> 6;
    for (int it = 0; it < TOPK; ++it) {
        float bv = -INFINITY;
        int bp = 0, bi = 0x7fffffff;
        for (int k = 0; k < 29; ++k) {
            int p = tid + (k << 8);
            if (p < NCAND) {
                float v = cs[p];
                int idx = ci[p];
                if (v > bv || (v == bv && idx < bi)) { bv = v; bi = idx; bp = p; }
            }
        }
        for (int off = 32; off; off >>= 1) {
            float ov = __shfl_down(bv, off);
            int oi = __shfl_down(bi, off);
            int op = __shfl_down(bp, off);
            if (ov > bv || (ov == bv && oi < bi)) { bv = ov; bi = oi; bp = op; }
        }
        if (lane == 0) { redv[wid] = bv; redp[wid] = bp; }
        __syncthreads();
        if (tid == 0) {
            for (int w2 = 1; w2 < 4; ++w2) {
                float ov = redv[w2]; int op = redp[w2];
                int oi = ci[op], mi = ci[bp];
                if (ov > bv || (ov == bv && oi < mi)) { bv = ov; bp = op; }
            }
            selv[it] = bv;
            seli[it] = ci[bp];
            cs[bp] = -INFINITY;
        }
        __syncthreads();
    }

    float smax = selv[0];  // first selected is the max
    float myp = 0.f;
    if (tid < TOPK) myp = expf(selv[tid] - smax);
    float s = myp;
    for (int off = 32; off; off >>= 1) s += __shfl_down(s, off);
    if (lane == 0) redsum[wid] = s;
    __syncthreads();
    float denom = redsum[0] + redsum[1] + redsum[2] + redsum[3];

    if (tid < TOPK) {
        int n = seli[tid];
        int f = n >> 11, l = n & (LL - 1);
        int l1 = l + 1 < LL ? l + 1 : LL - 1;
        int l2 = l + 2 < LL ? l + 2 : LL - 1;
        const float* r0 = x + ((size_t)(b * 2 + 0) * FF + f) * LL;
        const float* r1 = x + ((size_t)(b * 2 + 1) * FF + f) * LL;
        atomicAdd(&acc[0], myp * r0[l]);
        atomicAdd(&acc[1], myp * r1[l]);
        atomicAdd(&acc[2], myp * r0[l1]);
        atomicAdd(&acc[3], myp * r1[l1]);
        atomicAdd(&acc[4], myp * r0[l2]);
        atomicAdd(&acc[5], myp * r1[l2]);
    }
    __syncthreads();
    if (tid < 6) {
        float w = wv[0];
        float q = ws[OFF_Q + b * 6 + tid];
        out[b * 6 + tid] = (acc[tid] / denom) * w + q * (0.5f - w);
    }
}

extern "C" void kernel_launch(void* const* d_in, const int* in_sizes, int n_in,
                              void* d_out, int out_size, void* d_ws, size_t ws_size,
                              hipStream_t stream) {
    const float* x = (const float*)d_in[0];
    const float* w = (const float*)d_in[1];
    float* out = (float*)d_out;
    float* wsf = (float*)d_ws;
    int* wsi = (int*)d_ws;

    k_zero<<<1, 64, 0, stream>>>(wsf);
    k_rowsum<<<BATCH * 2 * FF, 256, 0, stream>>>(x, wsf);
    k_query<<<1, 64, 0, stream>>>(wsf);
    k_scores<<<BATCH * BPB, 256, 0, stream>>>(x, wsf, wsi);
    k_final<<<BATCH, 256, 0, stream>>>(x, w, wsf, wsi, out);
}

// Round 2
// 279.218 us; speedup vs baseline: 2.7881x; 2.7881x over previous
//
#include <hip/hip_runtime.h>
#include <math.h>

#define LL 2048
#define FF 352
#define BATCH 8
#define TOPK 84
#define FPB 4                 // f-rows per score block
#define BPB (FF / FPB)        // 88 blocks per batch
#define NBINS 8192
#define BINSCALE 1024.0f      // bin = score * 1024, range [0,8)
#define CAP 2048              // candidate buffer per batch

// ws int/float-index layout (regions disjoint)
#define OFF_A 0
#define OFF_B 16
#define OFF_C 32
#define OFF_D 48
#define OFF_Q 64                          // 48 floats
#define OFF_T 128                         // 8 ints: threshold bin per batch
#define OFF_CNT 136                       // 8 ints: candidate counters
#define OFF_HIST 256                      // 8*8192 ints
#define OFF_CS (256 + BATCH * NBINS)      // 8*2048 floats (candidate scores)
#define OFF_CI (OFF_CS + BATCH * CAP)     // 8*2048 ints  (candidate indices)
#define ZERO_END OFF_CS                   // zero [0, OFF_CS) ints

__global__ __launch_bounds__(256) void k_zero(int* wsi) {
    int idx = blockIdx.x * 256 + threadIdx.x;
    for (int p = idx; p < ZERO_END; p += 16384) wsi[p] = 0;
}

// One block per (b,ch,f) row: row sum -> A, plus x[0]->B, x[1]->C, x[L-1]->D
__global__ __launch_bounds__(256) void k_rowsum(const float* __restrict__ x,
                                                float* __restrict__ ws) {
    int r = blockIdx.x;              // (b*2+ch)*352 + f
    int bc = r / FF;
    const float4* rp = (const float4*)(x + (size_t)r * LL);
    int tid = threadIdx.x;
    float4 v0 = rp[tid];
    float4 v1 = rp[tid + 256];
    float s = v0.x + v0.y + v0.z + v0.w + v1.x + v1.y + v1.z + v1.w;
    for (int off = 32; off; off >>= 1) s += __shfl_down(s, off);
    __shared__ float red[4];
    int lane = tid & 63, wid = tid >> 6;
    if (lane == 0) red[wid] = s;
    __syncthreads();
    if (tid == 0) {
        atomicAdd(&ws[OFF_A + bc], red[0] + red[1] + red[2] + red[3]);
        atomicAdd(&ws[OFF_B + bc], v0.x);
        atomicAdd(&ws[OFF_C + bc], v0.y);
    }
    if (tid == 255) atomicAdd(&ws[OFF_D + bc], v1.w);
}

// query[b][e], e = i*2+ch: closed form of the shifted means
__global__ void k_query(float* ws) {
    int tid = threadIdx.x;
    if (tid < 48) {
        int e = tid % 6, i = e >> 1, ch = e & 1;
        int bc = (tid / 6) * 2 + ch;
        float A = ws[OFF_A + bc], B = ws[OFF_B + bc];
        float C = ws[OFF_C + bc], D = ws[OFF_D + bc];
        float S = (i == 0) ? A : (i == 1 ? A - B + D : A - B - C + 2.f * D);
        ws[OFF_Q + tid] = S * (1.f / (float)(FF * LL));
    }
}

// Pass 1: compute scores for 4 f-rows, histogram into LDS, flush to global
__global__ __launch_bounds__(256) void k_scorehist(const float* __restrict__ x,
                                                   const float* __restrict__ ws,
                                                   int* __restrict__ ghist) {
    __shared__ __align__(16) float rb0[LL + 2], rb1[LL + 2];
    __shared__ unsigned int hist[NBINS];
    int tid = threadIdx.x;
    int b = blockIdx.x / BPB, blk = blockIdx.x % BPB;
    int fb = blk * FPB;
    for (int k = 0; k < NBINS / 256; ++k) hist[tid + (k << 8)] = 0u;
    float q0 = ws[OFF_Q + b * 6 + 0], q1 = ws[OFF_Q + b * 6 + 1];
    float q2 = ws[OFF_Q + b * 6 + 2], q3 = ws[OFF_Q + b * 6 + 3];
    float q4 = ws[OFF_Q + b * 6 + 4], q5 = ws[OFF_Q + b * 6 + 5];

    for (int fr = 0; fr < FPB; ++fr) {
        int f = fb + fr;
        const float4* r0 = (const float4*)(x + ((size_t)(b * 2 + 0) * FF + f) * LL);
        const float4* r1 = (const float4*)(x + ((size_t)(b * 2 + 1) * FF + f) * LL);
        __syncthreads();
        float4 a0 = r0[tid], a1 = r0[tid + 256];
        float4 c0 = r1[tid], c1 = r1[tid + 256];
        ((float4*)rb0)[tid] = a0;
        ((float4*)rb0)[tid + 256] = a1;
        ((float4*)rb1)[tid] = c0;
        ((float4*)rb1)[tid + 256] = c1;
        if (tid == 255) {
            rb0[LL] = a1.w; rb0[LL + 1] = a1.w;
            rb1[LL] = c1.w; rb1[LL + 1] = c1.w;
        }
        __syncthreads();
        for (int k = 0; k < 8; ++k) {
            int l = tid + (k << 8);
            float s = q0 * rb0[l] + q1 * rb1[l]
                    + q2 * rb0[l + 1] + q3 * rb1[l + 1]
                    + q4 * rb0[l + 2] + q5 * rb1[l + 2];
            int bin = (int)(fmaxf(s, 0.f) * BINSCALE);
            bin = bin > NBINS - 1 ? NBINS - 1 : bin;
            atomicAdd(&hist[bin], 1u);
        }
    }
    __syncthreads();
    for (int k = 0; k < NBINS / 256; ++k) {
        int p = tid + (k << 8);
        unsigned int c = hist[p];
        if (c) atomicAdd(&ghist[b * NBINS + p], (int)c);
    }
}

// Find per-batch threshold bin t: suffix_count(t) >= TOPK > suffix_count(t+1)
__global__ __launch_bounds__(256) void k_thresh(const int* __restrict__ wsi,
                                                int* __restrict__ wt) {
    __shared__ int chunk[256];
    int tid = threadIdx.x;
    int b = blockIdx.x;
    const int* gh = wsi + OFF_HIST + b * NBINS;
    int csum = 0;
    for (int k = 0; k < 32; ++k) csum += gh[tid * 32 + k];
    chunk[tid] = csum;
    __syncthreads();
    if (tid == 0) {
        int cum = 0, c = 255;
        for (; c >= 0; --c) {
            cum += chunk[c];
            if (cum >= TOPK) break;
        }
        if (c < 0) c = 0;
        int cumBefore = cum - chunk[c];  // count in bins > chunk c's top
        int t = c * 32;
        int cum2 = cumBefore;
        for (int bin = c * 32 + 31; bin >= c * 32; --bin) {
            cum2 += gh[bin];
            if (cum2 >= TOPK) { t = bin; break; }
        }
        wt[OFF_T + b] = t;
    }
}

// Pass 2: recompute scores, compact candidates with bin >= t[b]
__global__ __launch_bounds__(256) void k_compact(const float* __restrict__ x,
                                                 const float* __restrict__ ws,
                                                 int* __restrict__ wsi,
                                                 float* __restrict__ wsf) {
    __shared__ __align__(16) float rb0[LL + 2], rb1[LL + 2];
    int tid = threadIdx.x;
    int b = blockIdx.x / BPB, blk = blockIdx.x % BPB;
    int fb = blk * FPB;
    int t = wsi[OFF_T + b];
    float thr = (float)t * (1.0f / BINSCALE);  // scores >= thr candidate (bin>=t iff s*1024>=t)
    float q0 = ws[OFF_Q + b * 6 + 0], q1 = ws[OFF_Q + b * 6 + 1];
    float q2 = ws[OFF_Q + b * 6 + 2], q3 = ws[OFF_Q + b * 6 + 3];
    float q4 = ws[OFF_Q + b * 6 + 4], q5 = ws[OFF_Q + b * 6 + 5];

    for (int fr = 0; fr < FPB; ++fr) {
        int f = fb + fr;
        const float4* r0 = (const float4*)(x + ((size_t)(b * 2 + 0) * FF + f) * LL);
        const float4* r1 = (const float4*)(x + ((size_t)(b * 2 + 1) * FF + f) * LL);
        __syncthreads();
        float4 a0 = r0[tid], a1 = r0[tid + 256];
        float4 c0 = r1[tid], c1 = r1[tid + 256];
        ((float4*)rb0)[tid] = a0;
        ((float4*)rb0)[tid + 256] = a1;
        ((float4*)rb1)[tid] = c0;
        ((float4*)rb1)[tid + 256] = c1;
        if (tid == 255) {
            rb0[LL] = a1.w; rb0[LL + 1] = a1.w;
            rb1[LL] = c1.w; rb1[LL + 1] = c1.w;
        }
        __syncthreads();
        for (int k = 0; k < 8; ++k) {
            int l = tid + (k << 8);
            float s = q0 * rb0[l] + q1 * rb1[l]
                    + q2 * rb0[l + 1] + q3 * rb1[l + 1]
                    + q4 * rb0[l + 2] + q5 * rb1[l + 2];
            int bin = (int)(fmaxf(s, 0.f) * BINSCALE);
            bin = bin > NBINS - 1 ? NBINS - 1 : bin;
            if (bin >= t) {
                int pos = atomicAdd(&wsi[OFF_CNT + b], 1);
                if (pos < CAP) {
                    wsf[OFF_CS + b * CAP + pos] = s;
                    wsi[OFF_CI + b * CAP + pos] = f * LL + l;
                }
            }
        }
    }
}

// One block per batch: exact rank-select top-84 among candidates, softmax, gather
__global__ __launch_bounds__(256) void k_final(const float* __restrict__ x,
                                               const float* __restrict__ wv,
                                               const float* __restrict__ ws,
                                               const int* __restrict__ wsi,
                                               float* __restrict__ out) {
    __shared__ float cs[CAP];
    __shared__ int ci[CAP];
    __shared__ float redm[4];
    __shared__ float den;
    __shared__ float acc[8];
    int tid = threadIdx.x;
    int b = blockIdx.x;
    int C = wsi[OFF_CNT + b];
    if (C > CAP) C = CAP;
    for (int p = tid; p < C; p += 256) {
        cs[p] = ws[OFF_CS + b * CAP + p];
        ci[p] = wsi[OFF_CI + b * CAP + p];
    }
    if (tid < 8) acc[tid] = 0.f;
    if (tid == 0) den = 0.f;
    __syncthreads();

    // block max for softmax stability
    float m = -INFINITY;
    for (int p = tid; p < C; p += 256) m = fmaxf(m, cs[p]);
    for (int off = 32; off; off >>= 1) m = fmaxf(m, __shfl_down(m, off));
    int lane = tid & 63, wid = tid >> 6;
    if (lane == 0) redm[wid] = m;
    __syncthreads();
    float smax = fmaxf(fmaxf(redm[0], redm[1]), fmaxf(redm[2], redm[3]));

    // rank-select: candidate selected iff fewer than TOPK candidates beat it
    for (int p = tid; p < C; p += 256) {
        float s = cs[p];
        int idx = ci[p];
        int rank = 0;
        for (int j = 0; j < C; ++j) {
            float sj = cs[j];
            int ij = ci[j];
            rank += (sj > s) || (sj == s && ij < idx);
        }
        if (rank < TOPK) {
            float pexp = expf(s - smax);
            atomicAdd(&den, pexp);
            int f = idx >> 11, l = idx & (LL - 1);
            int l1 = l + 1 < LL ? l + 1 : LL - 1;
            int l2 = l + 2 < LL ? l + 2 : LL - 1;
            const float* r0 = x + ((size_t)(b * 2 + 0) * FF + f) * LL;
            const float* r1 = x + ((size_t)(b * 2 + 1) * FF + f) * LL;
            atomicAdd(&acc[0], pexp * r0[l]);
            atomicAdd(&acc[1], pexp * r1[l]);
            atomicAdd(&acc[2], pexp * r0[l1]);
            atomicAdd(&acc[3], pexp * r1[l1]);
            atomicAdd(&acc[4], pexp * r0[l2]);
            atomicAdd(&acc[5], pexp * r1[l2]);
        }
    }
    __syncthreads();
    if (tid < 6) {
        float w = wv[0];
        float q = ws[OFF_Q + b * 6 + tid];
        out[b * 6 + tid] = (acc[tid] / den) * w + q * (0.5f - w);
    }
}

extern "C" void kernel_launch(void* const* d_in, const int* in_sizes, int n_in,
                              void* d_out, int out_size, void* d_ws, size_t ws_size,
                              hipStream_t stream) {
    const float* x = (const float*)d_in[0];
    const float* w = (const float*)d_in[1];
    float* out = (float*)d_out;
    float* wsf = (float*)d_ws;
    int* wsi = (int*)d_ws;

    k_zero<<<64, 256, 0, stream>>>(wsi);
    k_rowsum<<<BATCH * 2 * FF, 256, 0, stream>>>(x, wsf);
    k_query<<<1, 64, 0, stream>>>(wsf);
    k_scorehist<<<BATCH * BPB, 256, 0, stream>>>(x, wsf, wsi + OFF_HIST);
    k_thresh<<<BATCH, 256, 0, stream>>>(wsi, wsi);
    k_compact<<<BATCH * BPB, 256, 0, stream>>>(x, wsf, wsi, wsf);
    k_final<<<BATCH, 256, 0, stream>>>(x, w, wsf, wsi, out);
}

// Round 3
// 147.619 us; speedup vs baseline: 5.2737x; 1.8915x over previous
//
#include <hip/hip_runtime.h>
#include <math.h>

#define LL 2048
#define FF 352
#define BATCH 8
#define TOPK 84
#define FPB 4                 // f-rows per score block
#define BPB (FF / FPB)        // 88 blocks per batch
#define NBINS 8192
#define BINSCALE 1024.0f      // bin = score * 1024, range [0,8)
#define CAP 2048              // candidate buffer per batch
#define NROWS (BATCH * 2 * FF)  // 5632

// ws int/float-index layout (regions disjoint)
#define OFF_Q 64                              // 48 floats
#define OFF_T 128                             // 8 ints: threshold bin per batch
#define OFF_CNT 136                           // 8 ints: candidate counters
#define OFF_PART 256                          // 5632 float4 = 22528 floats
#define OFF_HIST (OFF_PART + NROWS * 4)       // 8*8192 ints
#define OFF_CS (OFF_HIST + BATCH * NBINS)     // 8*2048 floats (candidate scores)
#define OFF_CI (OFF_CS + BATCH * CAP)         // 8*2048 ints  (candidate indices)

__global__ __launch_bounds__(256) void k_zero(int* wsi) {
    int idx = blockIdx.x * 256 + threadIdx.x;
    for (int p = idx; p < BATCH * NBINS; p += 16384) wsi[OFF_HIST + p] = 0;
    if (idx < 8) wsi[OFF_CNT + idx] = 0;
}

// One block per (b,ch,f) row: partial = (rowsum, x[0], x[1], x[L-1]), no atomics
__global__ __launch_bounds__(256) void k_rowsum(const float* __restrict__ x,
                                                float* __restrict__ ws) {
    int r = blockIdx.x;              // (b*2+ch)*352 + f
    const float4* rp = (const float4*)(x + (size_t)r * LL);
    int tid = threadIdx.x;
    float4 v0 = rp[tid];
    float4 v1 = rp[tid + 256];
    float s = v0.x + v0.y + v0.z + v0.w + v1.x + v1.y + v1.z + v1.w;
    for (int off = 32; off; off >>= 1) s += __shfl_down(s, off);
    __shared__ float red[4];
    int lane = tid & 63, wid = tid >> 6;
    if (lane == 0) red[wid] = s;
    __syncthreads();
    float* part = ws + OFF_PART + 4 * r;
    if (tid == 0) {
        part[0] = red[0] + red[1] + red[2] + red[3];
        part[1] = v0.x;
        part[2] = v0.y;
    }
    if (tid == 255) part[3] = v1.w;
}

// One block per (b,ch): reduce 352 partials -> A,B,C,D -> 3 query elements
__global__ __launch_bounds__(256) void k_query(float* ws) {
    int tid = threadIdx.x;
    int bc = blockIdx.x;             // b*2+ch
    const float4* part = (const float4*)(ws + OFF_PART) + bc * FF;
    float4 s = part[tid];            // tid < 256 < 352 always valid
    if (tid < FF - 256) {
        float4 p2 = part[tid + 256];
        s.x += p2.x; s.y += p2.y; s.z += p2.z; s.w += p2.w;
    }
    for (int off = 32; off; off >>= 1) {
        s.x += __shfl_down(s.x, off);
        s.y += __shfl_down(s.y, off);
        s.z += __shfl_down(s.z, off);
        s.w += __shfl_down(s.w, off);
    }
    __shared__ float4 red[4];
    int lane = tid & 63, wid = tid >> 6;
    if (lane == 0) red[wid] = s;
    __syncthreads();
    if (tid == 0) {
        float A = red[0].x + red[1].x + red[2].x + red[3].x;
        float B = red[0].y + red[1].y + red[2].y + red[3].y;
        float C = red[0].z + red[1].z + red[2].z + red[3].z;
        float D = red[0].w + red[1].w + red[2].w + red[3].w;
        int b = bc >> 1, ch = bc & 1;
        const float inv = 1.f / (float)(FF * LL);
        ws[OFF_Q + b * 6 + 0 + ch] = A * inv;
        ws[OFF_Q + b * 6 + 2 + ch] = (A - B + D) * inv;
        ws[OFF_Q + b * 6 + 4 + ch] = (A - B - C + 2.f * D) * inv;
    }
}

// Pass 1: compute scores for 4 f-rows, histogram into LDS, flush to global
__global__ __launch_bounds__(256) void k_scorehist(const float* __restrict__ x,
                                                   const float* __restrict__ ws,
                                                   int* __restrict__ ghist) {
    __shared__ __align__(16) float rb0[LL + 2], rb1[LL + 2];
    __shared__ unsigned int hist[NBINS];
    int tid = threadIdx.x;
    int b = blockIdx.x / BPB, blk = blockIdx.x % BPB;
    int fb = blk * FPB;
    for (int k = 0; k < NBINS / 256; ++k) hist[tid + (k << 8)] = 0u;
    float q0 = ws[OFF_Q + b * 6 + 0], q1 = ws[OFF_Q + b * 6 + 1];
    float q2 = ws[OFF_Q + b * 6 + 2], q3 = ws[OFF_Q + b * 6 + 3];
    float q4 = ws[OFF_Q + b * 6 + 4], q5 = ws[OFF_Q + b * 6 + 5];

    for (int fr = 0; fr < FPB; ++fr) {
        int f = fb + fr;
        const float4* r0 = (const float4*)(x + ((size_t)(b * 2 + 0) * FF + f) * LL);
        const float4* r1 = (const float4*)(x + ((size_t)(b * 2 + 1) * FF + f) * LL);
        __syncthreads();
        float4 a0 = r0[tid], a1 = r0[tid + 256];
        float4 c0 = r1[tid], c1 = r1[tid + 256];
        ((float4*)rb0)[tid] = a0;
        ((float4*)rb0)[tid + 256] = a1;
        ((float4*)rb1)[tid] = c0;
        ((float4*)rb1)[tid + 256] = c1;
        if (tid == 255) {
            rb0[LL] = a1.w; rb0[LL + 1] = a1.w;
            rb1[LL] = c1.w; rb1[LL + 1] = c1.w;
        }
        __syncthreads();
        for (int k = 0; k < 8; ++k) {
            int l = tid + (k << 8);
            float s = q0 * rb0[l] + q1 * rb1[l]
                    + q2 * rb0[l + 1] + q3 * rb1[l + 1]
                    + q4 * rb0[l + 2] + q5 * rb1[l + 2];
            int bin = (int)(fmaxf(s, 0.f) * BINSCALE);
            bin = bin > NBINS - 1 ? NBINS - 1 : bin;
            atomicAdd(&hist[bin], 1u);
        }
    }
    __syncthreads();
    for (int k = 0; k < NBINS / 256; ++k) {
        int p = tid + (k << 8);
        unsigned int c = hist[p];
        if (c) atomicAdd(&ghist[b * NBINS + p], (int)c);
    }
}

// Find per-batch threshold bin t: suffix_count(t) >= TOPK > suffix_count(t+1)
__global__ __launch_bounds__(256) void k_thresh(const int* __restrict__ wsi,
                                                int* __restrict__ wt) {
    __shared__ int chunk[256];
    int tid = threadIdx.x;
    int b = blockIdx.x;
    const int* gh = wsi + OFF_HIST + b * NBINS;
    int csum = 0;
    for (int k = 0; k < 32; ++k) csum += gh[tid * 32 + k];
    chunk[tid] = csum;
    __syncthreads();
    if (tid == 0) {
        int cum = 0, c = 255;
        for (; c >= 0; --c) {
            cum += chunk[c];
            if (cum >= TOPK) break;
        }
        if (c < 0) c = 0;
        int cumBefore = cum - chunk[c];  // count in bins > chunk c's top
        int t = c * 32;
        int cum2 = cumBefore;
        for (int bin = c * 32 + 31; bin >= c * 32; --bin) {
            cum2 += gh[bin];
            if (cum2 >= TOPK) { t = bin; break; }
        }
        wt[OFF_T + b] = t;
    }
}

// Pass 2: recompute scores, compact candidates with bin >= t[b]
__global__ __launch_bounds__(256) void k_compact(const float* __restrict__ x,
                                                 const float* __restrict__ ws,
                                                 int* __restrict__ wsi,
                                                 float* __restrict__ wsf) {
    __shared__ __align__(16) float rb0[LL + 2], rb1[LL + 2];
    int tid = threadIdx.x;
    int b = blockIdx.x / BPB, blk = blockIdx.x % BPB;
    int fb = blk * FPB;
    int t = wsi[OFF_T + b];
    float q0 = ws[OFF_Q + b * 6 + 0], q1 = ws[OFF_Q + b * 6 + 1];
    float q2 = ws[OFF_Q + b * 6 + 2], q3 = ws[OFF_Q + b * 6 + 3];
    float q4 = ws[OFF_Q + b * 6 + 4], q5 = ws[OFF_Q + b * 6 + 5];

    for (int fr = 0; fr < FPB; ++fr) {
        int f = fb + fr;
        const float4* r0 = (const float4*)(x + ((size_t)(b * 2 + 0) * FF + f) * LL);
        const float4* r1 = (const float4*)(x + ((size_t)(b * 2 + 1) * FF + f) * LL);
        __syncthreads();
        float4 a0 = r0[tid], a1 = r0[tid + 256];
        float4 c0 = r1[tid], c1 = r1[tid + 256];
        ((float4*)rb0)[tid] = a0;
        ((float4*)rb0)[tid + 256] = a1;
        ((float4*)rb1)[tid] = c0;
        ((float4*)rb1)[tid + 256] = c1;
        if (tid == 255) {
            rb0[LL] = a1.w; rb0[LL + 1] = a1.w;
            rb1[LL] = c1.w; rb1[LL + 1] = c1.w;
        }
        __syncthreads();
        for (int k = 0; k < 8; ++k) {
            int l = tid + (k << 8);
            float s = q0 * rb0[l] + q1 * rb1[l]
                    + q2 * rb0[l + 1] + q3 * rb1[l + 1]
                    + q4 * rb0[l + 2] + q5 * rb1[l + 2];
            int bin = (int)(fmaxf(s, 0.f) * BINSCALE);
            bin = bin > NBINS - 1 ? NBINS - 1 : bin;
            if (bin >= t) {
                int pos = atomicAdd(&wsi[OFF_CNT + b], 1);
                if (pos < CAP) {
                    wsf[OFF_CS + b * CAP + pos] = s;
                    wsi[OFF_CI + b * CAP + pos] = f * LL + l;
                }
            }
        }
    }
}

// One block per batch: exact rank-select top-84 among candidates, softmax, gather
__global__ __launch_bounds__(256) void k_final(const float* __restrict__ x,
                                               const float* __restrict__ wv,
                                               const float* __restrict__ ws,
                                               const int* __restrict__ wsi,
                                               float* __restrict__ out) {
    __shared__ float cs[CAP];
    __shared__ int ci[CAP];
    __shared__ float redm[4];
    __shared__ float den;
    __shared__ float acc[8];
    int tid = threadIdx.x;
    int b = blockIdx.x;
    int C = wsi[OFF_CNT + b];
    if (C > CAP) C = CAP;
    for (int p = tid; p < C; p += 256) {
        cs[p] = ws[OFF_CS + b * CAP + p];
        ci[p] = wsi[OFF_CI + b * CAP + p];
    }
    if (tid < 8) acc[tid] = 0.f;
    if (tid == 0) den = 0.f;
    __syncthreads();

    // block max for softmax stability
    float m = -INFINITY;
    for (int p = tid; p < C; p += 256) m = fmaxf(m, cs[p]);
    for (int off = 32; off; off >>= 1) m = fmaxf(m, __shfl_down(m, off));
    int lane = tid & 63, wid = tid >> 6;
    if (lane == 0) redm[wid] = m;
    __syncthreads();
    float smax = fmaxf(fmaxf(redm[0], redm[1]), fmaxf(redm[2], redm[3]));

    // rank-select: candidate selected iff fewer than TOPK candidates beat it
    for (int p = tid; p < C; p += 256) {
        float s = cs[p];
        int idx = ci[p];
        int rank = 0;
        for (int j = 0; j < C; ++j) {
            float sj = cs[j];
            int ij = ci[j];
            rank += (sj > s) || (sj == s && ij < idx);
        }
        if (rank < TOPK) {
            float pexp = expf(s - smax);
            atomicAdd(&den, pexp);
            int f = idx >> 11, l = idx & (LL - 1);
            int l1 = l + 1 < LL ? l + 1 : LL - 1;
            int l2 = l + 2 < LL ? l + 2 : LL - 1;
            const float* r0 = x + ((size_t)(b * 2 + 0) * FF + f) * LL;
            const float* r1 = x + ((size_t)(b * 2 + 1) * FF + f) * LL;
            atomicAdd(&acc[0], pexp * r0[l]);
            atomicAdd(&acc[1], pexp * r1[l]);
            atomicAdd(&acc[2], pexp * r0[l1]);
            atomicAdd(&acc[3], pexp * r1[l1]);
            atomicAdd(&acc[4], pexp * r0[l2]);
            atomicAdd(&acc[5], pexp * r1[l2]);
        }
    }
    __syncthreads();
    if (tid < 6) {
        float w = wv[0];
        float q = ws[OFF_Q + b * 6 + tid];
        out[b * 6 + tid] = (acc[tid] / den) * w + q * (0.5f - w);
    }
}

extern "C" void kernel_launch(void* const* d_in, const int* in_sizes, int n_in,
                              void* d_out, int out_size, void* d_ws, size_t ws_size,
                              hipStream_t stream) {
    const float* x = (const float*)d_in[0];
    const float* w = (const float*)d_in[1];
    float* out = (float*)d_out;
    float* wsf = (float*)d_ws;
    int* wsi = (int*)d_ws;

    k_zero<<<64, 256, 0, stream>>>(wsi);
    k_rowsum<<<NROWS, 256, 0, stream>>>(x, wsf);
    k_query<<<BATCH * 2, 256, 0, stream>>>(wsf);
    k_scorehist<<<BATCH * BPB, 256, 0, stream>>>(x, wsf, wsi + OFF_HIST);
    k_thresh<<<BATCH, 256, 0, stream>>>(wsi, wsi);
    k_compact<<<BATCH * BPB, 256, 0, stream>>>(x, wsf, wsi, wsf);
    k_final<<<BATCH, 256, 0, stream>>>(x, w, wsf, wsi, out);
}

// Round 4
// 143.941 us; speedup vs baseline: 5.4084x; 1.0256x over previous
//
#include <hip/hip_runtime.h>
#include <math.h>

#define LL 2048
#define FF 352
#define BATCH 8
#define TOPK 84
#define FPB 4                   // f-rows per score block
#define BPB (FF / FPB)          // 88 blocks per batch
#define NBINS 8192
#define BINSCALE 1024.0f        // bin = score * 1024, range [0,8)
#define CAP 2048                // candidate buffer per batch
#define NROWS (BATCH * 2 * FF)  // 5632
#define FL (FF * LL)            // 720896 scores per batch

// ws int/float-index layout (regions disjoint)
#define OFF_Q 64                              // 48 floats (query)
#define OFF_CNT 136                           // 8 ints: candidate counters
#define OFF_PART 256                          // 5632 float4
#define OFF_HIST (OFF_PART + NROWS * 4)       // 8*8192 ints
#define OFF_CS (OFF_HIST + BATCH * NBINS)     // 8*2048 floats (candidate scores)
#define OFF_CI (OFF_CS + BATCH * CAP)         // 8*2048 ints  (candidate indices)
#define OFF_SC 131072                         // 8*720896 floats (cached scores)

// One block per (b,ch,f) row: partial = (rowsum, x[0], x[1], x[L-1]).
// First 256 blocks also zero the global histogram; block 256 zeroes counters.
__global__ __launch_bounds__(256) void k_rowsum(const float* __restrict__ x,
                                                float* __restrict__ ws,
                                                int* __restrict__ wsi) {
    int r = blockIdx.x;              // (b*2+ch)*352 + f
    int tid = threadIdx.x;
    if (r < 256) wsi[OFF_HIST + r * 256 + tid] = 0;
    if (r == 256 && tid < 8) wsi[OFF_CNT + tid] = 0;
    const float4* rp = (const float4*)(x + (size_t)r * LL);
    float4 v0 = rp[tid];
    float4 v1 = rp[tid + 256];
    float s = v0.x + v0.y + v0.z + v0.w + v1.x + v1.y + v1.z + v1.w;
    for (int off = 32; off; off >>= 1) s += __shfl_down(s, off);
    __shared__ float red[4];
    int lane = tid & 63, wid = tid >> 6;
    if (lane == 0) red[wid] = s;
    __syncthreads();
    float* part = ws + OFF_PART + 4 * r;
    if (tid == 0) {
        part[0] = red[0] + red[1] + red[2] + red[3];
        part[1] = v0.x;
        part[2] = v0.y;
    }
    if (tid == 255) part[3] = v1.w;
}

// One block per (b, f-block of 4): query prologue (reduce partials), then
// register-stencil scores -> cache to ws + LDS histogram -> global hist.
__global__ __launch_bounds__(256) void k_scorehist(const float* __restrict__ x,
                                                   float* __restrict__ ws,
                                                   int* __restrict__ wsi) {
    __shared__ unsigned int hist[NBINS];
    __shared__ float4 red0[4], red1[4];
    __shared__ float sq[6];
    int tid = threadIdx.x;
    int b = blockIdx.x / BPB, blk = blockIdx.x % BPB;
    int fb = blk * FPB;
    int lane = tid & 63, wid = tid >> 6;

    for (int k = 0; k < NBINS / 256; ++k) hist[tid + (k << 8)] = 0u;

    // ---- query prologue: reduce 704 partials for this batch ----
    float4 acc0 = {0.f, 0.f, 0.f, 0.f}, acc1 = {0.f, 0.f, 0.f, 0.f};
    const float4* part = (const float4*)(ws + OFF_PART) + b * 2 * FF;
    for (int i = tid; i < 2 * FF; i += 256) {
        float4 p = part[i];
        if (i < FF) { acc0.x += p.x; acc0.y += p.y; acc0.z += p.z; acc0.w += p.w; }
        else        { acc1.x += p.x; acc1.y += p.y; acc1.z += p.z; acc1.w += p.w; }
    }
    for (int off = 32; off; off >>= 1) {
        acc0.x += __shfl_down(acc0.x, off); acc0.y += __shfl_down(acc0.y, off);
        acc0.z += __shfl_down(acc0.z, off); acc0.w += __shfl_down(acc0.w, off);
        acc1.x += __shfl_down(acc1.x, off); acc1.y += __shfl_down(acc1.y, off);
        acc1.z += __shfl_down(acc1.z, off); acc1.w += __shfl_down(acc1.w, off);
    }
    if (lane == 0) { red0[wid] = acc0; red1[wid] = acc1; }
    __syncthreads();
    if (tid == 0) {
        float A0 = 0, B0 = 0, C0 = 0, D0 = 0, A1 = 0, B1 = 0, C1 = 0, D1 = 0;
        for (int w2 = 0; w2 < 4; ++w2) {
            A0 += red0[w2].x; B0 += red0[w2].y; C0 += red0[w2].z; D0 += red0[w2].w;
            A1 += red1[w2].x; B1 += red1[w2].y; C1 += red1[w2].z; D1 += red1[w2].w;
        }
        const float inv = 1.f / (float)FL;
        sq[0] = A0 * inv;
        sq[1] = A1 * inv;
        sq[2] = (A0 - B0 + D0) * inv;
        sq[3] = (A1 - B1 + D1) * inv;
        sq[4] = (A0 - B0 - C0 + 2.f * D0) * inv;
        sq[5] = (A1 - B1 - C1 + 2.f * D1) * inv;
        if (blk == 0) for (int e = 0; e < 6; ++e) ws[OFF_Q + b * 6 + e] = sq[e];
    }
    __syncthreads();
    float q0 = sq[0], q1 = sq[1], q2 = sq[2], q3 = sq[3], q4 = sq[4], q5 = sq[5];

    // ---- scores: register stencil, 4 scores/thread/half-row ----
    float* sc = ws + OFF_SC + (size_t)b * FL;
    for (int fr = 0; fr < FPB; ++fr) {
        int f = fb + fr;
        const float* r0 = x + ((size_t)(b * 2 + 0) * FF + f) * LL;
        const float* r1 = x + ((size_t)(b * 2 + 1) * FF + f) * LL;
        for (int h = 0; h < 2; ++h) {
            int l0 = (h << 10) + tid * 4;
            float4 u = *(const float4*)(r0 + l0);
            float4 v = *(const float4*)(r1 + l0);
            float a4 = __shfl_down(u.x, 1), a5 = __shfl_down(u.y, 1);
            float b4 = __shfl_down(v.x, 1), b5 = __shfl_down(v.y, 1);
            if (lane == 63) {
                if (l0 == LL - 4) { a4 = u.w; a5 = u.w; b4 = v.w; b5 = v.w; }
                else { a4 = r0[l0 + 4]; a5 = r0[l0 + 5];
                       b4 = r1[l0 + 4]; b5 = r1[l0 + 5]; }
            }
            float4 s;
            s.x = q0 * u.x + q1 * v.x + q2 * u.y + q3 * v.y + q4 * u.z + q5 * v.z;
            s.y = q0 * u.y + q1 * v.y + q2 * u.z + q3 * v.z + q4 * u.w + q5 * v.w;
            s.z = q0 * u.z + q1 * v.z + q2 * u.w + q3 * v.w + q4 * a4 + q5 * b4;
            s.w = q0 * u.w + q1 * v.w + q2 * a4 + q3 * b4 + q4 * a5 + q5 * b5;
            *(float4*)(sc + f * LL + l0) = s;
            #pragma unroll
            for (int j = 0; j < 4; ++j) {
                float sv = j == 0 ? s.x : (j == 1 ? s.y : (j == 2 ? s.z : s.w));
                int bin = (int)(fmaxf(sv, 0.f) * BINSCALE);
                bin = bin > NBINS - 1 ? NBINS - 1 : bin;
                atomicAdd(&hist[bin], 1u);
            }
        }
    }
    __syncthreads();
    for (int k = 0; k < NBINS / 256; ++k) {
        int p = tid + (k << 8);
        unsigned int c = hist[p];
        if (c) atomicAdd(&wsi[OFF_HIST + b * NBINS + p], (int)c);
    }
}

// One block per 8192-score chunk: threshold prologue + compact from cached scores
__global__ __launch_bounds__(256) void k_compact(float* __restrict__ ws,
                                                 int* __restrict__ wsi) {
    __shared__ int chunk[256];
    __shared__ int st;
    int tid = threadIdx.x;
    int b = blockIdx.x / BPB, blk = blockIdx.x % BPB;
    const int* gh = wsi + OFF_HIST + b * NBINS;

    // threshold: suffix_count(t) >= TOPK > suffix_count(t+1)
    const int4* gh4 = (const int4*)gh;
    int csum = 0;
    for (int k = 0; k < 8; ++k) {
        int4 q = gh4[tid * 8 + k];
        csum += q.x + q.y + q.z + q.w;
    }
    chunk[tid] = csum;
    __syncthreads();
    if (tid == 0) {
        int cum = 0, c = 255;
        for (; c >= 0; --c) {
            cum += chunk[c];
            if (cum >= TOPK) break;
        }
        if (c < 0) c = 0;
        int cum2 = cum - chunk[c];
        int t = c * 32;
        for (int bin = c * 32 + 31; bin >= c * 32; --bin) {
            cum2 += gh[bin];
            if (cum2 >= TOPK) { t = bin; break; }
        }
        st = t;
    }
    __syncthreads();
    int t = st;

    const float4* sc4 = (const float4*)(ws + OFF_SC + (size_t)b * FL) + blk * 2048;
    int nbase = blk * 8192;
    for (int k = 0; k < 8; ++k) {
        int idx4 = (k << 8) + tid;
        float4 s = sc4[idx4];
        #pragma unroll
        for (int j = 0; j < 4; ++j) {
            float sv = j == 0 ? s.x : (j == 1 ? s.y : (j == 2 ? s.z : s.w));
            int bin = (int)(fmaxf(sv, 0.f) * BINSCALE);
            bin = bin > NBINS - 1 ? NBINS - 1 : bin;
            if (bin >= t) {
                int pos = atomicAdd(&wsi[OFF_CNT + b], 1);
                if (pos < CAP) {
                    ws[OFF_CS + b * CAP + pos] = sv;
                    wsi[OFF_CI + b * CAP + pos] = nbase + idx4 * 4 + j;
                }
            }
        }
    }
}

// One block per batch: exact rank-select top-84, softmax, gather, output
__global__ __launch_bounds__(256) void k_final(const float* __restrict__ x,
                                               const float* __restrict__ wv,
                                               const float* __restrict__ ws,
                                               const int* __restrict__ wsi,
                                               float* __restrict__ out) {
    __shared__ float cs[CAP];
    __shared__ int ci[CAP];
    __shared__ float redm[4];
    __shared__ float den;
    __shared__ float acc[8];
    int tid = threadIdx.x;
    int b = blockIdx.x;
    int C = wsi[OFF_CNT + b];
    if (C > CAP) C = CAP;
    for (int p = tid; p < C; p += 256) {
        cs[p] = ws[OFF_CS + b * CAP + p];
        ci[p] = wsi[OFF_CI + b * CAP + p];
    }
    if (tid < 8) acc[tid] = 0.f;
    if (tid == 0) den = 0.f;
    __syncthreads();

    float m = -INFINITY;
    for (int p = tid; p < C; p += 256) m = fmaxf(m, cs[p]);
    for (int off = 32; off; off >>= 1) m = fmaxf(m, __shfl_down(m, off));
    int lane = tid & 63, wid = tid >> 6;
    if (lane == 0) redm[wid] = m;
    __syncthreads();
    float smax = fmaxf(fmaxf(redm[0], redm[1]), fmaxf(redm[2], redm[3]));

    for (int p = tid; p < C; p += 256) {
        float s = cs[p];
        int idx = ci[p];
        int rank = 0;
        for (int j = 0; j < C; ++j) {
            float sj = cs[j];
            int ij = ci[j];
            rank += (sj > s) || (sj == s && ij < idx);
        }
        if (rank < TOPK) {
            float pexp = expf(s - smax);
            atomicAdd(&den, pexp);
            int f = idx >> 11, l = idx & (LL - 1);
            int l1 = l + 1 < LL ? l + 1 : LL - 1;
            int l2 = l + 2 < LL ? l + 2 : LL - 1;
            const float* r0 = x + ((size_t)(b * 2 + 0) * FF + f) * LL;
            const float* r1 = x + ((size_t)(b * 2 + 1) * FF + f) * LL;
            atomicAdd(&acc[0], pexp * r0[l]);
            atomicAdd(&acc[1], pexp * r1[l]);
            atomicAdd(&acc[2], pexp * r0[l1]);
            atomicAdd(&acc[3], pexp * r1[l1]);
            atomicAdd(&acc[4], pexp * r0[l2]);
            atomicAdd(&acc[5], pexp * r1[l2]);
        }
    }
    __syncthreads();
    if (tid < 6) {
        float w = wv[0];
        float q = ws[OFF_Q + b * 6 + tid];
        out[b * 6 + tid] = (acc[tid] / den) * w + q * (0.5f - w);
    }
}

extern "C" void kernel_launch(void* const* d_in, const int* in_sizes, int n_in,
                              void* d_out, int out_size, void* d_ws, size_t ws_size,
                              hipStream_t stream) {
    const float* x = (const float*)d_in[0];
    const float* w = (const float*)d_in[1];
    float* out = (float*)d_out;
    float* wsf = (float*)d_ws;
    int* wsi = (int*)d_ws;

    k_rowsum<<<NROWS, 256, 0, stream>>>(x, wsf, wsi);
    k_scorehist<<<BATCH * BPB, 256, 0, stream>>>(x, wsf, wsi);
    k_compact<<<BATCH * BPB, 256, 0, stream>>>(wsf, wsi);
    k_final<<<BATCH, 256, 0, stream>>>(x, w, wsf, wsi, out);
}